// Round 9
// baseline (702.616 us; speedup 1.0000x reference)
//
#include <hip/hip_runtime.h>
#include <math.h>

// Problem constants (from reference setup_inputs)
#define N_ROWS 262144
#define DX 64
#define DZ 32
#define NB 1024
#define NBF 262144.0f
#define MIN_ASSIGN (0.1f / 1024.0f)
#define BIAS 512.0f
#define RPB 64                             // rows per encmin block

typedef short shortx8 __attribute__((ext_vector_type(8)));
typedef float floatx4 __attribute__((ext_vector_type(4)));
typedef float floatx2 __attribute__((ext_vector_type(2)));

// ---------- fast-path workspace layout (float offsets) ----------
#define WS_RECON  0
#define WS_COMMIT 1
#define WS_DONE   2                        // u32 done-counter
#define WS_VNORMB 64                       // + 1024  (vnorm + 512 bias)
#define WS_MUTAB  1088                     // + 1024*64 = 65536
#define WS_VBF    66624                    // 1024*32 bf16 = 16384 floats
#define WS_ZP     83008                    // 16 * 262144 u32 (bf16-pair z) = 4194304
#define WS_BIDX   4277312                  // 262144 u16 = 131072 floats
#define WS_SUMZC  4408384                  // 32*1024 comp-major z sums
#define WS_COUNTS 4441152                  // + 1024 (contiguous after SUMZC)
#define WS_TOTAL  4442176                  // floats (~17.8 MB)
#define HCHUNKS 32
#define HROWS  (N_ROWS / HCHUNKS)          // 8192 rows per chunk
#define HBLOCKS (17 * HCHUNKS)             // 544

// ---------- fallback (round-1) workspace layout ----------
#define FB_RECON  0
#define FB_COMMIT 1
#define FB_COUNTS 64
#define FB_SUMZ   1088
#define FB_VNORM  33856
#define FB_MUTAB  34880
#define FB_ZERO_N 33856

static __device__ __forceinline__ short f2bf(float f) {
    union { float f; unsigned u; } v; v.f = f;
    unsigned r = v.u + 0x7FFFu + ((v.u >> 16) & 1u);   // RNE
    return (short)(r >> 16);
}
static __device__ __forceinline__ float bits2f(unsigned u) {
    union { unsigned u; float f; } v; v.u = u; return v.f;
}

__global__ __launch_bounds__(256) void zero_kernel(float* __restrict__ p, int n) {
    int i = blockIdx.x * 256 + threadIdx.x;
    if (i < n) p[i] = 0.0f;
}

// Per-bin prep: biased vnorm, mu_table row, bf16 codebook.
// Also zero-inits sum_z/counts (33792 floats) + recon/commit/done.
__global__ __launch_bounds__(64) void vq_prep(
    const float* __restrict__ vectors, const float* __restrict__ W_dec,
    const float* __restrict__ b_dec, float* __restrict__ ws)
{
    const int j = blockIdx.x;
    const int t = threadIdx.x;
    float* vnormb = ws + WS_VNORMB;
    float* mu_table = ws + WS_MUTAB;
    short* vbf = (short*)(ws + WS_VBF);

    const int flat = j * 64 + t;
    if (flat < 33792) (ws + WS_SUMZC)[flat] = 0.0f;    // sum_z + counts
    if (j == 0 && t < 3) ws[t] = 0.0f;                 // recon, commit, done

    __shared__ float v[DZ];
    if (t < DZ) {
        float vv = vectors[j * DZ + t];
        v[t] = vv;
        vbf[j * DZ + t] = f2bf(vv);
    }
    __syncthreads();
    float m = b_dec[t];
    #pragma unroll
    for (int k = 0; k < DZ; ++k) m = fmaf(v[k], W_dec[k * DX + t], m);
    mu_table[(size_t)j * DX + t] = m;
    if (t == 0) {
        float s = 0.0f;
        #pragma unroll
        for (int k = 0; k < DZ; ++k) s = fmaf(v[k], v[k], s);
        vnormb[j] = s + BIAS;
    }
}

// ---------- fused encoder + MFMA argmin + epilogue, j-split waves ----------
// Block = 64 rows, 256 threads (4 waves). x staged once in padded LDS
// (coalesced; reused by encoder AND epilogue). Encoder c-split: thread
// (row, q) computes z[q*8..q*8+8). Wave w scans codes [w*256,(w+1)*256)
// with packed-key min; per-row merge across waves via LDS.
__global__ __launch_bounds__(256, 6) void vq_encmin(
    const float* __restrict__ x, const float* __restrict__ W_enc,
    const float* __restrict__ b_enc, const short* __restrict__ vbf,
    const float* __restrict__ vnormb, const float* __restrict__ mutab,
    unsigned* __restrict__ zp, unsigned short* __restrict__ bidx_out,
    float* __restrict__ recon_acc, float* __restrict__ commit_acc)
{
    __shared__ float xs[RPB * 65];                                // 16.25 KB (pad 65)
    __shared__ __attribute__((aligned(16))) short zbf[RPB * 40];  //  5 KB
    __shared__ float vnl[NB];                                     //  4 KB
    __shared__ unsigned skey[256];                                //  1 KB
    const int t = threadIdx.x;
    const int w = t >> 6, l = t & 63;
    const int rl = l >> 2;              // row within wave's 16-row set
    const int q  = l & 3;               // component/k quarter
    const int row = w * 16 + rl;        // 0..63 within block
    const int r = blockIdx.x * RPB + row;

    // stage biased vnorm
    ((float4*)vnl)[t] = ((const float4*)vnormb)[t];

    // stage x block (64x64 f32) coalesced, pad-65 rows to spread banks
    {
        const float4* xg = (const float4*)(x + (size_t)blockIdx.x * RPB * DX);
        #pragma unroll
        for (int i = 0; i < 4; ++i) {
            int f4 = i * 256 + t;                 // float4 index 0..1023
            float4 v = xg[f4];
            int rr = f4 >> 4, cc = (f4 & 15) * 4;
            float* d = &xs[rr * 65 + cc];
            d[0] = v.x; d[1] = v.y; d[2] = v.z; d[3] = v.w;
        }
    }
    __syncthreads();

    // ---- phase 1: encoder (c-split), z comps q*8..q*8+8 ----
    floatx2 z2[4];
    #pragma unroll
    for (int i = 0; i < 4; ++i)
        z2[i] = *(const floatx2*)&b_enc[q * 8 + 2 * i];
    const float* xrow = &xs[row * 65];
    #pragma unroll 8
    for (int k = 0; k < DX; ++k) {
        float xk = xrow[k];
        floatx2 xk2 = {xk, xk};
        const floatx2* wr = (const floatx2*)&W_enc[k * DZ + q * 8];
        #pragma unroll
        for (int i = 0; i < 4; ++i)
            z2[i] = __builtin_elementwise_fma(xk2, wr[i], z2[i]);
    }
    floatx2 zn2 = {0.0f, 0.0f};
    #pragma unroll
    for (int i = 0; i < 4; ++i)
        zn2 = __builtin_elementwise_fma(z2[i], z2[i], zn2);
    float znp = zn2.x + zn2.y;
    znp += __shfl_xor(znp, 1, 64);
    znp += __shfl_xor(znp, 2, 64);
    const float znorm = znp;                      // full ||z||^2 on all 4 lanes

    #pragma unroll
    for (int i = 0; i < 4; ++i) {
        unsigned lo = (unsigned short)f2bf(z2[i].x);
        unsigned hi = (unsigned short)f2bf(z2[i].y);
        zp[(size_t)(q * 4 + i) * N_ROWS + r] = lo | (hi << 16);
        unsigned l2 = (unsigned short)f2bf(-2.0f * z2[i].x);
        unsigned h2 = (unsigned short)f2bf(-2.0f * z2[i].y);
        *(unsigned*)&zbf[row * 40 + q * 8 + 2 * i] = l2 | (h2 << 16);
    }
    __syncthreads();

    // ---- phase 2: wave w scans codes [w*256, w*256+256) over all 64 rows ----
    const int lm = l & 15, lq = l >> 4;
    shortx8 afrag[4];
    #pragma unroll
    for (int rt = 0; rt < 4; ++rt)
        afrag[rt] = *(const shortx8*)&zbf[(rt * 16 + lm) * 40 + lq * 8];

    unsigned key[16];
    #pragma unroll
    for (int k = 0; k < 16; ++k) key[k] = 0xFFFFFFFFu;

    const short* vb = vbf + (w * 256 + lm) * DZ + lq * 8;
    #pragma unroll 1
    for (int p = 0; p < 4; ++p) {
        shortx8 bb[4];
        #pragma unroll
        for (int jt = 0; jt < 4; ++jt)
            bb[jt] = *(const shortx8*)(vb + (p * 64 + jt * 16) * DZ);
        #pragma unroll
        for (int jt = 0; jt < 4; ++jt) {
            const int jbase = w * 256 + p * 64 + jt * 16 + lm;
            float vn = vnl[jbase];
            floatx4 cin = {vn, vn, vn, vn};
            #pragma unroll
            for (int rt = 0; rt < 4; ++rt) {
                floatx4 acc = __builtin_amdgcn_mfma_f32_16x16x32_bf16(
                    afrag[rt], bb[jt], cin, 0, 0, 0);
                #pragma unroll
                for (int reg = 0; reg < 4; ++reg) {
                    unsigned u = __builtin_bit_cast(unsigned, acc[reg]);
                    unsigned pk = (u & 0xFFFFFC00u) | (unsigned)jbase;
                    int k = rt * 4 + reg;
                    key[k] = key[k] < pk ? key[k] : pk;
                }
            }
        }
    }
    #pragma unroll
    for (int k = 0; k < 16; ++k) {
        unsigned kv = key[k];
        #pragma unroll
        for (int m = 1; m <= 8; m <<= 1) {
            unsigned ov = __shfl_xor(kv, m, 64);
            kv = ov < kv ? ov : kv;
        }
        if (lm == 0)                               // rows rt*16 + lq*4 + reg
            skey[w * 64 + (k >> 2) * 16 + lq * 4 + (k & 3)] = kv;
    }
    __syncthreads();

    // ---- phase 3: epilogue (thread (row,q), x from LDS) ----
    unsigned kr = skey[row];
    {
        unsigned k1 = skey[64 + row], k2 = skey[128 + row], k3 = skey[192 + row];
        kr = k1 < kr ? k1 : kr;
        kr = k2 < kr ? k2 : kr;
        kr = k3 < kr ? k3 : kr;
    }
    const int bsel = (int)(kr & 1023u);
    const float score = bits2f(kr & 0xFFFFFC00u);
    float commit = (q == 0) ? (znorm + (score - BIAS)) : 0.0f;
    if (q == 0) bidx_out[r] = (unsigned short)bsel;

    float rs = 0.0f;
    const float*  xr2 = &xs[row * 65 + q * 16];
    const float4* mp  = (const float4*)(mutab + (size_t)bsel * DX + q * 16);
    #pragma unroll
    for (int i = 0; i < 4; ++i) {
        float4 m = mp[i];
        float d0 = xr2[4 * i + 0] - m.x; rs = fmaf(d0, d0, rs);
        float d1 = xr2[4 * i + 1] - m.y; rs = fmaf(d1, d1, rs);
        float d2 = xr2[4 * i + 2] - m.z; rs = fmaf(d2, d2, rs);
        float d3 = xr2[4 * i + 3] - m.w; rs = fmaf(d3, d3, rs);
    }
    #pragma unroll
    for (int off = 32; off > 0; off >>= 1) {
        rs     += __shfl_down(rs, off, 64);
        commit += __shfl_down(commit, off, 64);
    }
    if (l == 0) {
        atomicAdd(recon_acc, rs);
        atomicAdd(commit_acc, commit);
    }
}

// ---------- hist + reduce + finalize in ONE kernel (last-block-done) ----------
__global__ __launch_bounds__(256) void vq_histfin(
    const unsigned* __restrict__ zp, const unsigned short* __restrict__ bidx,
    const float* __restrict__ vectors, const float* __restrict__ assignments,
    const float* __restrict__ noise, float* __restrict__ ws,
    float* __restrict__ out)
{
    __shared__ float h[2 * NB];
    __shared__ int sdone;
    __shared__ int s_mx;
    const int t = threadIdx.x;
    const int ci    = blockIdx.x % 17;
    const int chunk = blockIdx.x / 17;
    float* sumzc  = ws + WS_SUMZC;
    float* counts = ws + WS_COUNTS;

    #pragma unroll
    for (int i = 0; i < 8; ++i) h[t + 256 * i] = 0.0f;
    __syncthreads();

    const int base = chunk * HROWS;
    if (ci < 16) {
        const unsigned* zc = zp + (size_t)ci * N_ROWS;
        for (int i = 0; i < HROWS / 256; ++i) {
            int r = base + t + 256 * i;
            unsigned w = zc[r];
            int b = bidx[r];
            atomicAdd(&h[b],      bits2f(w << 16));
            atomicAdd(&h[b + NB], bits2f(w & 0xFFFF0000u));
        }
        __syncthreads();
        float* d0 = sumzc + (size_t)(2 * ci) * NB;
        float* d1 = d0 + NB;
        #pragma unroll
        for (int i = 0; i < 4; ++i) {
            atomicAdd(&d0[t + 256 * i], h[t + 256 * i]);
            atomicAdd(&d1[t + 256 * i], h[NB + t + 256 * i]);
        }
    } else {
        for (int i = 0; i < HROWS / 256; ++i) {
            int r = base + t + 256 * i;
            atomicAdd(&h[bidx[r]], 1.0f);
        }
        __syncthreads();
        #pragma unroll
        for (int i = 0; i < 4; ++i)
            atomicAdd(&counts[t + 256 * i], h[t + 256 * i]);
    }

    __syncthreads();
    if (t == 0) {
        __threadfence();
        unsigned old = atomicAdd((unsigned*)ws + WS_DONE, 1u);
        sdone = (old == HBLOCKS - 1) ? 1 : 0;
    }
    __syncthreads();
    if (!sdone) return;
    __threadfence();

    // ---- finalize: 256 threads, bins 4t..4t+3 (reuse h as scratch) ----
    float* af           = h;
    unsigned char* dd   = (unsigned char*)(h + 1024);
    int*   tsum         = (int*)(h + 1280);
    float* rv           = h + 1536;
    int*   ri           = (int*)(h + 1792);

    float cnt[4]; int dloc[4];
    float bestv = -1.0f; int besti = 0;
    #pragma unroll
    for (int u = 0; u < 4; ++u) {
        int b = 4 * t + u;
        float c = counts[b]; cnt[u] = c;
        float ba = c / NBF;
        float ae = 0.99f * assignments[b] + 0.01f * ba;
        af[b] = ae;
        int d = (ae * NBF < MIN_ASSIGN) ? 1 : 0;
        dd[b] = (unsigned char)d; dloc[u] = d;
        if (ba > bestv) { bestv = ba; besti = b; }
    }
    rv[t] = bestv; ri[t] = besti;
    __syncthreads();
    for (int s = 128; s > 0; s >>= 1) {
        if (t < s) {
            float ov = rv[t + s]; int oi = ri[t + s];
            if (ov > rv[t] || (ov == rv[t] && oi < ri[t])) { rv[t] = ov; ri[t] = oi; }
        }
        __syncthreads();
    }
    if (t == 0) s_mx = ri[0];
    __syncthreads();
    const int mx = s_mx;
    const float a0mx = af[mx];
    const int na_mx = dd[mx];

    tsum[t] = dloc[0] + dloc[1] + dloc[2] + dloc[3];
    __syncthreads();
    for (int off = 1; off < 256; off <<= 1) {
        int v2 = (t + off < 256) ? tsum[t + off] : 0;
        __syncthreads();
        tsum[t] += v2;
        __syncthreads();
    }
    const int K = tsum[0];
    const int Snext = (t < 255) ? tsum[t + 1] : 0;
    int suf[4];
    suf[3] = dloc[3]; suf[2] = dloc[2] + suf[3];
    suf[1] = dloc[1] + suf[2]; suf[0] = dloc[0] + suf[1];

    #pragma unroll
    for (int u = 0; u < 4; ++u) {
        int b = 4 * t + u;
        float av = af[b];
        int rank = suf[u] + Snext;
        int isd = dd[b];
        if (isd) av = ldexpf(a0mx, -rank);
        if (b == mx && K > 0) av = ldexpf(a0mx, -K);
        out[1 + NB * DZ + b] = av;

        const float mxn = (isd && b < mx && na_mx) ? 1.0f : 0.0f;
        #pragma unroll
        for (int c = 0; c < DZ; ++c) {
            float v2 = vectors[b * DZ + c];
            if (isd) v2 = vectors[mx * DZ + c] + mxn * noise[mx * DZ + c]
                          + noise[b * DZ + c];
            float mean = (cnt[u] == 0.0f) ? v2 : (sumzc[(size_t)c * NB + b] / cnt[u]);
            out[1 + b * DZ + c] = 0.99f * v2 + 0.01f * mean;
        }
    }
    if (t == 0) {
        float recon = 0.5f * (ws[WS_RECON] / NBF) + 32.0f * 1.8378770664093453f;
        float commit = ws[WS_COMMIT] / (NBF * (float)DZ);
        out[0] = recon + 0.25f * commit;
    }
}

// ---------- fallback (round-1) path, used only if ws is too small ----------
__global__ __launch_bounds__(64) void vq_prep_fb(
    const float* __restrict__ vectors, const float* __restrict__ W_dec,
    const float* __restrict__ b_dec, float* __restrict__ vnorm,
    float* __restrict__ mu_table)
{
    const int j = blockIdx.x;
    const int t = threadIdx.x;
    __shared__ float v[DZ];
    if (t < DZ) v[t] = vectors[j * DZ + t];
    __syncthreads();
    float m = b_dec[t];
    #pragma unroll
    for (int k = 0; k < DZ; ++k) m = fmaf(v[k], W_dec[k * DX + t], m);
    mu_table[(size_t)j * DX + t] = m;
    if (t == 0) {
        float s = 0.0f;
        #pragma unroll
        for (int k = 0; k < DZ; ++k) s = fmaf(v[k], v[k], s);
        vnorm[j] = s;
    }
}

__global__ __launch_bounds__(256) void vq_main_atomic(
    const float* __restrict__ x, const float* __restrict__ W_enc,
    const float* __restrict__ b_enc, const float* __restrict__ vectors,
    const float* __restrict__ vnorm, const float* __restrict__ mu_table,
    float* __restrict__ counts, float* __restrict__ sum_z,
    float* __restrict__ recon_acc, float* __restrict__ commit_acc)
{
    const int r = blockIdx.x * 256 + threadIdx.x;
    float xr[DX];
    const float4* xp = reinterpret_cast<const float4*>(x + (size_t)r * DX);
    #pragma unroll
    for (int i = 0; i < DX / 4; ++i) {
        float4 v = xp[i];
        xr[4 * i + 0] = v.x; xr[4 * i + 1] = v.y;
        xr[4 * i + 2] = v.z; xr[4 * i + 3] = v.w;
    }
    float z[DZ];
    #pragma unroll
    for (int c = 0; c < DZ; ++c) z[c] = b_enc[c];
    #pragma unroll
    for (int k = 0; k < DX; ++k) {
        float xk = xr[k];
        #pragma unroll
        for (int c = 0; c < DZ; ++c) z[c] = fmaf(xk, W_enc[k * DZ + c], z[c]);
    }
    float znorm = 0.0f;
    #pragma unroll
    for (int c = 0; c < DZ; ++c) znorm = fmaf(z[c], z[c], znorm);
    float zm2[DZ];
    #pragma unroll
    for (int c = 0; c < DZ; ++c) zm2[c] = -2.0f * z[c];

    float best = 3.4e38f;
    int bi = 0;
    for (int j = 0; j < NB; ++j) {
        const float* vj = vectors + j * DZ;
        float s0 = vnorm[j], s1 = 0.0f, s2 = 0.0f, s3 = 0.0f;
        #pragma unroll
        for (int c = 0; c < DZ; c += 4) {
            s0 = fmaf(zm2[c + 0], vj[c + 0], s0);
            s1 = fmaf(zm2[c + 1], vj[c + 1], s1);
            s2 = fmaf(zm2[c + 2], vj[c + 2], s2);
            s3 = fmaf(zm2[c + 3], vj[c + 3], s3);
        }
        float s = (s0 + s1) + (s2 + s3);
        if (s < best) { best = s; bi = j; }
    }
    float commit_row = znorm + best;

    float rs = 0.0f;
    const float4* mup = reinterpret_cast<const float4*>(mu_table + (size_t)bi * DX);
    #pragma unroll
    for (int i = 0; i < DX / 4; ++i) {
        float4 m = mup[i];
        float d0 = xr[4 * i + 0] - m.x; rs = fmaf(d0, d0, rs);
        float d1 = xr[4 * i + 1] - m.y; rs = fmaf(d1, d1, rs);
        float d2 = xr[4 * i + 2] - m.z; rs = fmaf(d2, d2, rs);
        float d3 = xr[4 * i + 3] - m.w; rs = fmaf(d3, d3, rs);
    }
    atomicAdd(&counts[bi], 1.0f);
    #pragma unroll
    for (int c = 0; c < DZ; ++c)
        atomicAdd(&sum_z[(size_t)bi * DZ + c], -0.5f * zm2[c]);
    #pragma unroll
    for (int off = 32; off > 0; off >>= 1) {
        rs += __shfl_down(rs, off, 64);
        commit_row += __shfl_down(commit_row, off, 64);
    }
    if ((threadIdx.x & 63) == 0) {
        atomicAdd(recon_acc, rs);
        atomicAdd(commit_acc, commit_row);
    }
}

__global__ __launch_bounds__(1024) void vq_finalize_fb(
    const float* __restrict__ vectors, const float* __restrict__ assignments,
    const float* __restrict__ noise, const float* __restrict__ counts,
    const float* __restrict__ sum_z, const float* __restrict__ recon_acc,
    const float* __restrict__ commit_acc, float* __restrict__ out)
{
    __shared__ float a[NB];
    __shared__ unsigned char na[NB];
    __shared__ float rv[NB];
    __shared__ int ri[NB];
    __shared__ int s_max_idx;
    const int t = threadIdx.x;

    const float cnt = counts[t];
    const float ba = cnt / NBF;
    const float ae = 0.99f * assignments[t] + 0.01f * ba;
    a[t] = ae;
    na[t] = (ae * NBF < MIN_ASSIGN) ? 1 : 0;
    rv[t] = ba; ri[t] = t;
    __syncthreads();
    for (int s = NB / 2; s > 0; s >>= 1) {
        if (t < s) {
            float ov = rv[t + s]; int oi = ri[t + s];
            if (ov > rv[t] || (ov == rv[t] && oi < ri[t])) { rv[t] = ov; ri[t] = oi; }
        }
        __syncthreads();
    }
    if (t == 0) s_max_idx = ri[0];
    __syncthreads();
    const int mx = s_max_idx;
    if (t == 0) {
        for (int i = NB - 1; i >= 0; --i) {
            if (na[i]) { float v = 0.5f * a[mx]; a[i] = v; a[mx] = v; }
        }
    }
    __syncthreads();
    out[1 + NB * DZ + t] = a[t];
    const bool dead = (na[t] != 0);
    #pragma unroll
    for (int c = 0; c < DZ; ++c) {
        float v2 = dead ? (vectors[mx * DZ + c] + noise[t * DZ + c])
                        : vectors[t * DZ + c];
        float mean = (cnt == 0.0f) ? v2 : (sum_z[(size_t)t * DZ + c] / cnt);
        out[1 + t * DZ + c] = 0.99f * v2 + 0.01f * mean;
    }
    if (t == 0) {
        float recon = 0.5f * (recon_acc[0] / NBF) + 32.0f * 1.8378770664093453f;
        float commit = commit_acc[0] / (NBF * (float)DZ);
        out[0] = recon + 0.25f * commit;
    }
}

extern "C" void kernel_launch(void* const* d_in, const int* in_sizes, int n_in,
                              void* d_out, int out_size, void* d_ws, size_t ws_size,
                              hipStream_t stream)
{
    const float* x           = (const float*)d_in[0];
    const float* W_enc       = (const float*)d_in[1];
    const float* b_enc       = (const float*)d_in[2];
    const float* vectors     = (const float*)d_in[3];
    const float* W_dec       = (const float*)d_in[4];
    const float* b_dec       = (const float*)d_in[5];
    const float* assignments = (const float*)d_in[6];
    const float* noise       = (const float*)d_in[7];
    float* out = (float*)d_out;
    float* ws  = (float*)d_ws;

    if (ws_size >= (size_t)WS_TOTAL * sizeof(float)) {
        vq_prep<<<NB, 64, 0, stream>>>(vectors, W_dec, b_dec, ws);
        vq_encmin<<<N_ROWS / RPB, 256, 0, stream>>>(x, W_enc, b_enc,
            (const short*)(ws + WS_VBF), ws + WS_VNORMB, ws + WS_MUTAB,
            (unsigned*)(ws + WS_ZP), (unsigned short*)(ws + WS_BIDX),
            ws + WS_RECON, ws + WS_COMMIT);
        vq_histfin<<<HBLOCKS, 256, 0, stream>>>(
            (const unsigned*)(ws + WS_ZP),
            (const unsigned short*)(ws + WS_BIDX),
            vectors, assignments, noise, ws, out);
    } else {
        zero_kernel<<<(FB_ZERO_N + 255) / 256, 256, 0, stream>>>(ws, FB_ZERO_N);
        vq_prep_fb<<<NB, 64, 0, stream>>>(vectors, W_dec, b_dec,
            ws + FB_VNORM, ws + FB_MUTAB);
        vq_main_atomic<<<N_ROWS / 256, 256, 0, stream>>>(x, W_enc, b_enc, vectors,
            ws + FB_VNORM, ws + FB_MUTAB, ws + FB_COUNTS, ws + FB_SUMZ,
            ws + FB_RECON, ws + FB_COMMIT);
        vq_finalize_fb<<<1, NB, 0, stream>>>(vectors, assignments, noise,
            ws + FB_COUNTS, ws + FB_SUMZ, ws + FB_RECON, ws + FB_COMMIT, out);
    }
}

// Round 10
// 375.993 us; speedup vs baseline: 1.8687x; 1.8687x over previous
//
#include <hip/hip_runtime.h>
#include <math.h>

// Problem constants (from reference setup_inputs)
#define N_ROWS 262144
#define DX 64
#define DZ 32
#define NB 1024
#define NBF 262144.0f
#define MIN_ASSIGN (0.1f / 1024.0f)
#define BIAS 512.0f

typedef short shortx8 __attribute__((ext_vector_type(8)));
typedef float floatx4 __attribute__((ext_vector_type(4)));
typedef float floatx2 __attribute__((ext_vector_type(2)));

// ---------- fast-path workspace layout (float offsets) ----------
#define WS_RECON  0
#define WS_COMMIT 1
#define WS_DONE   2                        // u32 done-counter
#define WS_VNORMB 64                       // + 1024  (vnorm + 512 bias)
#define WS_MUTAB  1088                     // + 1024*64 = 65536
#define WS_VBF    66624                    // 1024*32 bf16 = 16384 floats
#define WS_ZP     83008                    // 16 * 262144 u32 (bf16-pair z) = 4194304
#define WS_BIDX   4277312                  // 262144 u16 = 131072 floats
#define WS_SUMZC  4408384                  // 32*1024 comp-major z sums
#define WS_COUNTS 4441152                  // + 1024 (contiguous after SUMZC)
#define WS_TOTAL  4442176                  // floats (~17.8 MB)
#define HCHUNKS 32
#define HROWS  (N_ROWS / HCHUNKS)          // 8192 rows per chunk
#define HBLOCKS (17 * HCHUNKS)             // 544

// ---------- fallback (round-1) workspace layout ----------
#define FB_RECON  0
#define FB_COMMIT 1
#define FB_COUNTS 64
#define FB_SUMZ   1088
#define FB_VNORM  33856
#define FB_MUTAB  34880
#define FB_ZERO_N 33856

static __device__ __forceinline__ short f2bf(float f) {
    union { float f; unsigned u; } v; v.f = f;
    unsigned r = v.u + 0x7FFFu + ((v.u >> 16) & 1u);   // RNE
    return (short)(r >> 16);
}
static __device__ __forceinline__ float bits2f(unsigned u) {
    union { unsigned u; float f; } v; v.u = u; return v.f;
}

__global__ __launch_bounds__(256) void zero_kernel(float* __restrict__ p, int n) {
    int i = blockIdx.x * 256 + threadIdx.x;
    if (i < n) p[i] = 0.0f;
}

// Per-bin prep: biased vnorm, mu_table row, bf16 codebook.
// Also zero-inits sum_z/counts (33792 floats) + recon/commit/done.
__global__ __launch_bounds__(64) void vq_prep(
    const float* __restrict__ vectors, const float* __restrict__ W_dec,
    const float* __restrict__ b_dec, float* __restrict__ ws)
{
    const int j = blockIdx.x;
    const int t = threadIdx.x;
    float* vnormb = ws + WS_VNORMB;
    float* mu_table = ws + WS_MUTAB;
    short* vbf = (short*)(ws + WS_VBF);

    const int flat = j * 64 + t;
    if (flat < 33792) (ws + WS_SUMZC)[flat] = 0.0f;    // sum_z + counts
    if (j == 0 && t < 3) ws[t] = 0.0f;                 // recon, commit, done

    __shared__ float v[DZ];
    if (t < DZ) {
        float vv = vectors[j * DZ + t];
        v[t] = vv;
        vbf[j * DZ + t] = f2bf(vv);
    }
    __syncthreads();
    float m = b_dec[t];
    #pragma unroll
    for (int k = 0; k < DZ; ++k) m = fmaf(v[k], W_dec[k * DX + t], m);
    mu_table[(size_t)j * DX + t] = m;
    if (t == 0) {
        float s = 0.0f;
        #pragma unroll
        for (int k = 0; k < DZ; ++k) s = fmaf(v[k], v[k], s);
        vnormb[j] = s + BIAS;
    }
}

// ---------- fused encoder + MFMA argmin + epilogue ----------
// 256 rows/block, 1 row/thread (r7 structure). Phase 2 stages the codebook
// through LDS in 4 chunks of 256 codes (r3's proven pattern, ~12cyc LDS reads
// vs ~250cyc L2), with vnorm folded into the 40-short row pad. skey aliases
// zbf (all zbf reads complete before any skey write). LDS total = 40960 B
// exactly -> 4 blocks/CU at VGPR<=64.
__global__ __launch_bounds__(256, 4) void vq_encmin(
    const float* __restrict__ x, const float* __restrict__ W_enc,
    const float* __restrict__ b_enc, const short* __restrict__ vbf,
    const float* __restrict__ vnormb, const float* __restrict__ mutab,
    unsigned* __restrict__ zp, unsigned short* __restrict__ bidx_out,
    float* __restrict__ recon_acc, float* __restrict__ commit_acc)
{
    __shared__ __attribute__((aligned(16))) short zbf[256 * 40];    // 20480 B
    __shared__ __attribute__((aligned(16))) short vchunk[256 * 40]; // 20480 B
    unsigned* skey = (unsigned*)zbf;   // alias: zbf reads all precede skey writes
    const int t = threadIdx.x;
    const int r = blockIdx.x * 256 + t;

    // ---- phase 1: fp32 encoder (packed float2 fma, wave-uniform W_enc s_loads) ----
    floatx2 z2[16];
    #pragma unroll
    for (int c2 = 0; c2 < 16; ++c2)
        z2[c2] = *(const floatx2*)&b_enc[2 * c2];
    #pragma unroll 1
    for (int h = 0; h < 2; ++h) {
        float xr[32];
        const float4* xp = (const float4*)(x + (size_t)r * DX + h * 32);
        #pragma unroll
        for (int i = 0; i < 8; ++i) {
            float4 vv = xp[i];
            xr[4 * i + 0] = vv.x; xr[4 * i + 1] = vv.y;
            xr[4 * i + 2] = vv.z; xr[4 * i + 3] = vv.w;
        }
        #pragma unroll
        for (int kk = 0; kk < 32; ++kk) {
            floatx2 xk2 = {xr[kk], xr[kk]};
            const floatx2* wrow = (const floatx2*)&W_enc[(h * 32 + kk) * DZ];
            #pragma unroll
            for (int c2 = 0; c2 < 16; ++c2)
                z2[c2] = __builtin_elementwise_fma(xk2, wrow[c2], z2[c2]);
        }
    }
    floatx2 zn2 = {0.0f, 0.0f};
    #pragma unroll
    for (int c2 = 0; c2 < 16; ++c2)
        zn2 = __builtin_elementwise_fma(z2[c2], z2[c2], zn2);
    const float znorm = zn2.x + zn2.y;

    #pragma unroll
    for (int c2 = 0; c2 < 16; ++c2) {
        unsigned lo = (unsigned short)f2bf(z2[c2].x);
        unsigned hi = (unsigned short)f2bf(z2[c2].y);
        zp[(size_t)c2 * N_ROWS + r] = lo | (hi << 16);     // coalesced per-plane
        unsigned l2 = (unsigned short)f2bf(-2.0f * z2[c2].x);
        unsigned h2 = (unsigned short)f2bf(-2.0f * z2[c2].y);
        *(unsigned*)&zbf[t * 40 + 2 * c2] = l2 | (h2 << 16);
    }
    __syncthreads();

    // ---- phase 2: MFMA argmin, codebook chunked through LDS ----
    const int w = t >> 6, l = t & 63, lm = l & 15, lq = l >> 4;
    shortx8 afrag[4];
    #pragma unroll
    for (int rt = 0; rt < 4; ++rt)
        afrag[rt] = *(const shortx8*)&zbf[(w * 64 + rt * 16 + lm) * 40 + lq * 8];

    unsigned key[16];
    #pragma unroll
    for (int k = 0; k < 16; ++k) key[k] = 0xFFFFFFFFu;

    #pragma unroll 1
    for (int chunk = 0; chunk < 4; ++chunk) {
        __syncthreads();               // vchunk free (prev chunk consumed)
        // cooperative stage: 256 codes x 32 bf16 -> padded 40-short rows
        const shortx8* src = (const shortx8*)(vbf + chunk * 256 * DZ);
        #pragma unroll
        for (int i = 0; i < 4; ++i) {
            int u = i * 256 + t;
            int code = u >> 2, part = u & 3;
            *(shortx8*)&vchunk[code * 40 + part * 8] = src[u];
        }
        // fold biased vnorm into the row pad (shorts 32..33)
        {
            float vn = vnormb[chunk * 256 + t];
            *(unsigned*)&vchunk[t * 40 + 32] = __builtin_bit_cast(unsigned, vn);
        }
        __syncthreads();

        #pragma unroll 4
        for (int jt = 0; jt < 16; ++jt) {
            const int vrow = (jt * 16 + lm) * 40;
            shortx8 bfrag = *(const shortx8*)&vchunk[vrow + lq * 8];
            float vn = bits2f(*(const unsigned*)&vchunk[vrow + 32]);
            const int jbase = chunk * 256 + jt * 16 + lm;
            floatx4 cin = {vn, vn, vn, vn};
            #pragma unroll
            for (int rt = 0; rt < 4; ++rt) {
                floatx4 acc = __builtin_amdgcn_mfma_f32_16x16x32_bf16(
                    afrag[rt], bfrag, cin, 0, 0, 0);
                #pragma unroll
                for (int reg = 0; reg < 4; ++reg) {
                    unsigned u = __builtin_bit_cast(unsigned, acc[reg]);
                    unsigned pk = (u & 0xFFFFFC00u) | (unsigned)jbase;
                    int k = rt * 4 + reg;
                    key[k] = key[k] < pk ? key[k] : pk;
                }
            }
        }
    }

    // cross-lane min over the 16 columns (lm bits); ties -> smaller j
    #pragma unroll
    for (int k = 0; k < 16; ++k) {
        unsigned kv = key[k];
        #pragma unroll
        for (int m = 1; m <= 8; m <<= 1) {
            unsigned ov = __shfl_xor(kv, m, 64);
            kv = ov < kv ? ov : kv;
        }
        if (lm == 0)
            skey[w * 64 + (k >> 2) * 16 + lq * 4 + (k & 3)] = kv;
    }
    __syncthreads();

    // ---- phase 3: epilogue ----
    const unsigned kr = skey[t];
    const int bsel = (int)(kr & 1023u);
    const float score = bits2f(kr & 0xFFFFFC00u);
    float commit = znorm + (score - BIAS);
    bidx_out[r] = (unsigned short)bsel;

    float rs = 0.0f;
    const float4* xp2 = (const float4*)(x + (size_t)r * DX);
    const float4* mp  = (const float4*)(mutab + (size_t)bsel * DX);
    #pragma unroll
    for (int i = 0; i < DX / 4; ++i) {
        float4 xv = xp2[i];
        float4 m  = mp[i];
        float d0 = xv.x - m.x; rs = fmaf(d0, d0, rs);
        float d1 = xv.y - m.y; rs = fmaf(d1, d1, rs);
        float d2 = xv.z - m.z; rs = fmaf(d2, d2, rs);
        float d3 = xv.w - m.w; rs = fmaf(d3, d3, rs);
    }
    #pragma unroll
    for (int off = 32; off > 0; off >>= 1) {
        rs     += __shfl_down(rs, off, 64);
        commit += __shfl_down(commit, off, 64);
    }
    if (l == 0) {
        atomicAdd(recon_acc, rs);
        atomicAdd(commit_acc, commit);
    }
}

// ---------- hist + reduce + finalize in ONE kernel (last-block-done) ----------
__global__ __launch_bounds__(256) void vq_histfin(
    const unsigned* __restrict__ zp, const unsigned short* __restrict__ bidx,
    const float* __restrict__ vectors, const float* __restrict__ assignments,
    const float* __restrict__ noise, float* __restrict__ ws,
    float* __restrict__ out)
{
    __shared__ float h[2 * NB];
    __shared__ int sdone;
    __shared__ int s_mx;
    const int t = threadIdx.x;
    const int ci    = blockIdx.x % 17;
    const int chunk = blockIdx.x / 17;
    float* sumzc  = ws + WS_SUMZC;
    float* counts = ws + WS_COUNTS;

    #pragma unroll
    for (int i = 0; i < 8; ++i) h[t + 256 * i] = 0.0f;
    __syncthreads();

    const int base = chunk * HROWS;
    if (ci < 16) {
        const unsigned* zc = zp + (size_t)ci * N_ROWS;
        for (int i = 0; i < HROWS / 256; ++i) {
            int r = base + t + 256 * i;
            unsigned w = zc[r];
            int b = bidx[r];
            atomicAdd(&h[b],      bits2f(w << 16));
            atomicAdd(&h[b + NB], bits2f(w & 0xFFFF0000u));
        }
        __syncthreads();
        float* d0 = sumzc + (size_t)(2 * ci) * NB;
        float* d1 = d0 + NB;
        #pragma unroll
        for (int i = 0; i < 4; ++i) {
            atomicAdd(&d0[t + 256 * i], h[t + 256 * i]);
            atomicAdd(&d1[t + 256 * i], h[NB + t + 256 * i]);
        }
    } else {
        for (int i = 0; i < HROWS / 256; ++i) {
            int r = base + t + 256 * i;
            atomicAdd(&h[bidx[r]], 1.0f);
        }
        __syncthreads();
        #pragma unroll
        for (int i = 0; i < 4; ++i)
            atomicAdd(&counts[t + 256 * i], h[t + 256 * i]);
    }

    __syncthreads();
    if (t == 0) {
        __threadfence();
        unsigned old = atomicAdd((unsigned*)ws + WS_DONE, 1u);
        sdone = (old == HBLOCKS - 1) ? 1 : 0;
    }
    __syncthreads();
    if (!sdone) return;
    __threadfence();

    // ---- finalize: 256 threads, bins 4t..4t+3 (reuse h as scratch) ----
    float* af           = h;
    unsigned char* dd   = (unsigned char*)(h + 1024);
    int*   tsum         = (int*)(h + 1280);
    float* rv           = h + 1536;
    int*   ri           = (int*)(h + 1792);

    float cnt[4]; int dloc[4];
    float bestv = -1.0f; int besti = 0;
    #pragma unroll
    for (int u = 0; u < 4; ++u) {
        int b = 4 * t + u;
        float c = counts[b]; cnt[u] = c;
        float ba = c / NBF;
        float ae = 0.99f * assignments[b] + 0.01f * ba;
        af[b] = ae;
        int d = (ae * NBF < MIN_ASSIGN) ? 1 : 0;
        dd[b] = (unsigned char)d; dloc[u] = d;
        if (ba > bestv) { bestv = ba; besti = b; }
    }
    rv[t] = bestv; ri[t] = besti;
    __syncthreads();
    for (int s = 128; s > 0; s >>= 1) {
        if (t < s) {
            float ov = rv[t + s]; int oi = ri[t + s];
            if (ov > rv[t] || (ov == rv[t] && oi < ri[t])) { rv[t] = ov; ri[t] = oi; }
        }
        __syncthreads();
    }
    if (t == 0) s_mx = ri[0];
    __syncthreads();
    const int mx = s_mx;
    const float a0mx = af[mx];
    const int na_mx = dd[mx];

    tsum[t] = dloc[0] + dloc[1] + dloc[2] + dloc[3];
    __syncthreads();
    for (int off = 1; off < 256; off <<= 1) {
        int v2 = (t + off < 256) ? tsum[t + off] : 0;
        __syncthreads();
        tsum[t] += v2;
        __syncthreads();
    }
    const int K = tsum[0];
    const int Snext = (t < 255) ? tsum[t + 1] : 0;
    int suf[4];
    suf[3] = dloc[3]; suf[2] = dloc[2] + suf[3];
    suf[1] = dloc[1] + suf[2]; suf[0] = dloc[0] + suf[1];

    #pragma unroll
    for (int u = 0; u < 4; ++u) {
        int b = 4 * t + u;
        float av = af[b];
        int rank = suf[u] + Snext;
        int isd = dd[b];
        if (isd) av = ldexpf(a0mx, -rank);
        if (b == mx && K > 0) av = ldexpf(a0mx, -K);
        out[1 + NB * DZ + b] = av;

        const float mxn = (isd && b < mx && na_mx) ? 1.0f : 0.0f;
        #pragma unroll
        for (int c = 0; c < DZ; ++c) {
            float v2 = vectors[b * DZ + c];
            if (isd) v2 = vectors[mx * DZ + c] + mxn * noise[mx * DZ + c]
                          + noise[b * DZ + c];
            float mean = (cnt[u] == 0.0f) ? v2 : (sumzc[(size_t)c * NB + b] / cnt[u]);
            out[1 + b * DZ + c] = 0.99f * v2 + 0.01f * mean;
        }
    }
    if (t == 0) {
        float recon = 0.5f * (ws[WS_RECON] / NBF) + 32.0f * 1.8378770664093453f;
        float commit = ws[WS_COMMIT] / (NBF * (float)DZ);
        out[0] = recon + 0.25f * commit;
    }
}

// ---------- fallback (round-1) path, used only if ws is too small ----------
__global__ __launch_bounds__(64) void vq_prep_fb(
    const float* __restrict__ vectors, const float* __restrict__ W_dec,
    const float* __restrict__ b_dec, float* __restrict__ vnorm,
    float* __restrict__ mu_table)
{
    const int j = blockIdx.x;
    const int t = threadIdx.x;
    __shared__ float v[DZ];
    if (t < DZ) v[t] = vectors[j * DZ + t];
    __syncthreads();
    float m = b_dec[t];
    #pragma unroll
    for (int k = 0; k < DZ; ++k) m = fmaf(v[k], W_dec[k * DX + t], m);
    mu_table[(size_t)j * DX + t] = m;
    if (t == 0) {
        float s = 0.0f;
        #pragma unroll
        for (int k = 0; k < DZ; ++k) s = fmaf(v[k], v[k], s);
        vnorm[j] = s;
    }
}

__global__ __launch_bounds__(256) void vq_main_atomic(
    const float* __restrict__ x, const float* __restrict__ W_enc,
    const float* __restrict__ b_enc, const float* __restrict__ vectors,
    const float* __restrict__ vnorm, const float* __restrict__ mu_table,
    float* __restrict__ counts, float* __restrict__ sum_z,
    float* __restrict__ recon_acc, float* __restrict__ commit_acc)
{
    const int r = blockIdx.x * 256 + threadIdx.x;
    float xr[DX];
    const float4* xp = reinterpret_cast<const float4*>(x + (size_t)r * DX);
    #pragma unroll
    for (int i = 0; i < DX / 4; ++i) {
        float4 v = xp[i];
        xr[4 * i + 0] = v.x; xr[4 * i + 1] = v.y;
        xr[4 * i + 2] = v.z; xr[4 * i + 3] = v.w;
    }
    float z[DZ];
    #pragma unroll
    for (int c = 0; c < DZ; ++c) z[c] = b_enc[c];
    #pragma unroll
    for (int k = 0; k < DX; ++k) {
        float xk = xr[k];
        #pragma unroll
        for (int c = 0; c < DZ; ++c) z[c] = fmaf(xk, W_enc[k * DZ + c], z[c]);
    }
    float znorm = 0.0f;
    #pragma unroll
    for (int c = 0; c < DZ; ++c) znorm = fmaf(z[c], z[c], znorm);
    float zm2[DZ];
    #pragma unroll
    for (int c = 0; c < DZ; ++c) zm2[c] = -2.0f * z[c];

    float best = 3.4e38f;
    int bi = 0;
    for (int j = 0; j < NB; ++j) {
        const float* vj = vectors + j * DZ;
        float s0 = vnorm[j], s1 = 0.0f, s2 = 0.0f, s3 = 0.0f;
        #pragma unroll
        for (int c = 0; c < DZ; c += 4) {
            s0 = fmaf(zm2[c + 0], vj[c + 0], s0);
            s1 = fmaf(zm2[c + 1], vj[c + 1], s1);
            s2 = fmaf(zm2[c + 2], vj[c + 2], s2);
            s3 = fmaf(zm2[c + 3], vj[c + 3], s3);
        }
        float s = (s0 + s1) + (s2 + s3);
        if (s < best) { best = s; bi = j; }
    }
    float commit_row = znorm + best;

    float rs = 0.0f;
    const float4* mup = reinterpret_cast<const float4*>(mu_table + (size_t)bi * DX);
    #pragma unroll
    for (int i = 0; i < DX / 4; ++i) {
        float4 m = mup[i];
        float d0 = xr[4 * i + 0] - m.x; rs = fmaf(d0, d0, rs);
        float d1 = xr[4 * i + 1] - m.y; rs = fmaf(d1, d1, rs);
        float d2 = xr[4 * i + 2] - m.z; rs = fmaf(d2, d2, rs);
        float d3 = xr[4 * i + 3] - m.w; rs = fmaf(d3, d3, rs);
    }
    atomicAdd(&counts[bi], 1.0f);
    #pragma unroll
    for (int c = 0; c < DZ; ++c)
        atomicAdd(&sum_z[(size_t)bi * DZ + c], -0.5f * zm2[c]);
    #pragma unroll
    for (int off = 32; off > 0; off >>= 1) {
        rs += __shfl_down(rs, off, 64);
        commit_row += __shfl_down(commit_row, off, 64);
    }
    if ((threadIdx.x & 63) == 0) {
        atomicAdd(recon_acc, rs);
        atomicAdd(commit_acc, commit_row);
    }
}

__global__ __launch_bounds__(1024) void vq_finalize_fb(
    const float* __restrict__ vectors, const float* __restrict__ assignments,
    const float* __restrict__ noise, const float* __restrict__ counts,
    const float* __restrict__ sum_z, const float* __restrict__ recon_acc,
    const float* __restrict__ commit_acc, float* __restrict__ out)
{
    __shared__ float a[NB];
    __shared__ unsigned char na[NB];
    __shared__ float rv[NB];
    __shared__ int ri[NB];
    __shared__ int s_max_idx;
    const int t = threadIdx.x;

    const float cnt = counts[t];
    const float ba = cnt / NBF;
    const float ae = 0.99f * assignments[t] + 0.01f * ba;
    a[t] = ae;
    na[t] = (ae * NBF < MIN_ASSIGN) ? 1 : 0;
    rv[t] = ba; ri[t] = t;
    __syncthreads();
    for (int s = NB / 2; s > 0; s >>= 1) {
        if (t < s) {
            float ov = rv[t + s]; int oi = ri[t + s];
            if (ov > rv[t] || (ov == rv[t] && oi < ri[t])) { rv[t] = ov; ri[t] = oi; }
        }
        __syncthreads();
    }
    if (t == 0) s_max_idx = ri[0];
    __syncthreads();
    const int mx = s_max_idx;
    if (t == 0) {
        for (int i = NB - 1; i >= 0; --i) {
            if (na[i]) { float v = 0.5f * a[mx]; a[i] = v; a[mx] = v; }
        }
    }
    __syncthreads();
    out[1 + NB * DZ + t] = a[t];
    const bool dead = (na[t] != 0);
    #pragma unroll
    for (int c = 0; c < DZ; ++c) {
        float v2 = dead ? (vectors[mx * DZ + c] + noise[t * DZ + c])
                        : vectors[t * DZ + c];
        float mean = (cnt == 0.0f) ? v2 : (sum_z[(size_t)t * DZ + c] / cnt);
        out[1 + t * DZ + c] = 0.99f * v2 + 0.01f * mean;
    }
    if (t == 0) {
        float recon = 0.5f * (recon_acc[0] / NBF) + 32.0f * 1.8378770664093453f;
        float commit = commit_acc[0] / (NBF * (float)DZ);
        out[0] = recon + 0.25f * commit;
    }
}

extern "C" void kernel_launch(void* const* d_in, const int* in_sizes, int n_in,
                              void* d_out, int out_size, void* d_ws, size_t ws_size,
                              hipStream_t stream)
{
    const float* x           = (const float*)d_in[0];
    const float* W_enc       = (const float*)d_in[1];
    const float* b_enc       = (const float*)d_in[2];
    const float* vectors     = (const float*)d_in[3];
    const float* W_dec       = (const float*)d_in[4];
    const float* b_dec       = (const float*)d_in[5];
    const float* assignments = (const float*)d_in[6];
    const float* noise       = (const float*)d_in[7];
    float* out = (float*)d_out;
    float* ws  = (float*)d_ws;

    if (ws_size >= (size_t)WS_TOTAL * sizeof(float)) {
        vq_prep<<<NB, 64, 0, stream>>>(vectors, W_dec, b_dec, ws);
        vq_encmin<<<N_ROWS / 256, 256, 0, stream>>>(x, W_enc, b_enc,
            (const short*)(ws + WS_VBF), ws + WS_VNORMB, ws + WS_MUTAB,
            (unsigned*)(ws + WS_ZP), (unsigned short*)(ws + WS_BIDX),
            ws + WS_RECON, ws + WS_COMMIT);
        vq_histfin<<<HBLOCKS, 256, 0, stream>>>(
            (const unsigned*)(ws + WS_ZP),
            (const unsigned short*)(ws + WS_BIDX),
            vectors, assignments, noise, ws, out);
    } else {
        zero_kernel<<<(FB_ZERO_N + 255) / 256, 256, 0, stream>>>(ws, FB_ZERO_N);
        vq_prep_fb<<<NB, 64, 0, stream>>>(vectors, W_dec, b_dec,
            ws + FB_VNORM, ws + FB_MUTAB);
        vq_main_atomic<<<N_ROWS / 256, 256, 0, stream>>>(x, W_enc, b_enc, vectors,
            ws + FB_VNORM, ws + FB_MUTAB, ws + FB_COUNTS, ws + FB_SUMZ,
            ws + FB_RECON, ws + FB_COMMIT);
        vq_finalize_fb<<<1, NB, 0, stream>>>(vectors, assignments, noise,
            ws + FB_COUNTS, ws + FB_SUMZ, ws + FB_RECON, ws + FB_COMMIT, out);
    }
}